// Round 3
// baseline (330.962 us; speedup 1.0000x reference)
//
#include <hip/hip_runtime.h>
#include <math.h>

#define T_   2048
#define NB_  64
#define NU_  8
#define NY_  8
#define NH_  256
#define H2_  128
#define CCH  128     // number of chunks
#define LCH  16      // chunk length = T_/CCH
#define TT_  2       // time tile in k_emit

#define BUF_FLOATS (CCH*NB_*H2_*2)   // [k][b][h2][2] = 2M floats = 8 MB
static const float PI_HALF = 1.5707963267948966f;

// Lane j owns pair j (channels j, j+128) and pair j+64 (channels j+64, j+192).

// ---------------- kernel 1: local chunk scan (zero init) ----------------
__global__ __launch_bounds__(64, 8) void k_local(
    const float* __restrict__ U, const float* __restrict__ lr,
    const float* __restrict__ li, const float* __restrict__ B,
    const float* __restrict__ mult, float* __restrict__ c_buf)
{
    const int k = blockIdx.x >> 6;
    const int b = blockIdx.x & 63;
    const int j = threadIdx.x;

    float r1  = expf(-fabsf(lr[j]));
    float t1  = PI_HALF * li[j];
    float re1 = r1 * cosf(t1), im1 = r1 * sinf(t1);
    float r2  = expf(-fabsf(lr[j+64]));
    float t2  = PI_HALF * li[j+64];
    float re2 = r2 * cosf(t2), im2 = r2 * sinf(t2);

    float B1[NU_], B2[NU_], B3[NU_], B4[NU_];
    {
        float s1 = expf(mult[j]),      s2 = expf(mult[j+128]);
        float s3 = expf(mult[j+64]),   s4 = expf(mult[j+192]);
        #pragma unroll
        for (int i = 0; i < NU_; i++) {
            B1[i] = B[(j      )*NU_ + i] * s1;
            B2[i] = B[(j + 128)*NU_ + i] * s2;
            B3[i] = B[(j +  64)*NU_ + i] * s3;
            B4[i] = B[(j + 192)*NU_ + i] * s4;
        }
    }

    __shared__ float uS[LCH*NU_];   // [16][8]
    if (j < 32) {
        int t = j >> 1, half = j & 1;
        float4 v = *(const float4*)(U + ((size_t)(k*LCH + t)*NB_ + b)*NU_ + half*4);
        ((float4*)uS)[j] = v;
    }
    __syncthreads();

    float x1a=0.f, x2a=0.f, x1b=0.f, x2b=0.f;
    #pragma unroll
    for (int t = 0; t < LCH; t++) {
        float4 u0 = ((const float4*)uS)[2*t+0];
        float4 u1 = ((const float4*)uS)[2*t+1];
        float u[NU_] = {u0.x,u0.y,u0.z,u0.w,u1.x,u1.y,u1.z,u1.w};
        float bu1=0.f, bu2=0.f, bu3=0.f, bu4=0.f;
        #pragma unroll
        for (int i = 0; i < NU_; i++) {
            bu1 = fmaf(u[i], B1[i], bu1);
            bu2 = fmaf(u[i], B2[i], bu2);
            bu3 = fmaf(u[i], B3[i], bu3);
            bu4 = fmaf(u[i], B4[i], bu4);
        }
        float n1a = fmaf(re1, x1a, fmaf(-im1, x2a, bu1));
        float n2a = fmaf(im1, x1a, fmaf( re1, x2a, bu2));
        float n1b = fmaf(re2, x1b, fmaf(-im2, x2b, bu3));
        float n2b = fmaf(im2, x1b, fmaf( re2, x2b, bu4));
        x1a=n1a; x2a=n2a; x1b=n1b; x2b=n2b;
    }

    float* base = c_buf + ((size_t)(k*NB_ + b))*(H2_*2);
    *(float2*)(base + 2*j)       = make_float2(x1a, x2a);
    *(float2*)(base + 128 + 2*j) = make_float2(x1b, x2b);
}

// ---------------- kernel 2: chunk prefix combine (separate in/out bufs) -------
__global__ __launch_bounds__(64) void k_prefix(
    const float* __restrict__ y0, const float* __restrict__ lr,
    const float* __restrict__ li, const float* __restrict__ Wy2x,
    const float* __restrict__ by2x, const float* __restrict__ c_buf,
    float* __restrict__ init_buf)
{
    const int g = blockIdx.x*64 + threadIdx.x;   // 0..8191
    const int b = g >> 7;
    const int h = g & 127;

    float x1 = by2x[h], x2 = by2x[h+H2_];
    #pragma unroll
    for (int y = 0; y < NY_; y++) {
        float yy = y0[b*NY_ + y];
        x1 = fmaf(yy, Wy2x[h*NY_ + y],        x1);
        x2 = fmaf(yy, Wy2x[(h+H2_)*NY_ + y],  x2);
    }

    float rL  = expf(-(float)LCH * fabsf(lr[h]));
    float thL = (float)LCH * PI_HALF * li[h];
    float reL = rL * cosf(thL), imL = rL * sinf(thL);

    const size_t stride = NB_*(size_t)(H2_*2);
    const size_t off    = (size_t)b*(H2_*2) + 2*h;

    #pragma unroll 8
    for (int k = 0; k < CCH; k++) {
        float2 c = *(const float2*)(c_buf + k*stride + off);   // independent loads
        *(float2*)(init_buf + k*stride + off) = make_float2(x1, x2);
        float n1 = fmaf(reL, x1, fmaf(-imL, x2, c.x));
        float n2 = fmaf(imL, x1, fmaf( reL, x2, c.y));
        x1 = n1; x2 = n2;
    }
}

// ---------------- kernel 3: replay with true init + tiled projection ----------
__global__ __launch_bounds__(64, 8) void k_emit(
    const float* __restrict__ U, const float* __restrict__ lr,
    const float* __restrict__ li, const float* __restrict__ B,
    const float* __restrict__ mult, const float* __restrict__ Wx2y,
    const float* __restrict__ bx2y, const float* __restrict__ init_buf,
    float* __restrict__ Y)
{
    const int k = blockIdx.x >> 6;
    const int b = blockIdx.x & 63;
    const int j = threadIdx.x;

    float r1  = expf(-fabsf(lr[j]));
    float t1  = PI_HALF * li[j];
    float re1 = r1 * cosf(t1), im1 = r1 * sinf(t1);
    float r2  = expf(-fabsf(lr[j+64]));
    float t2  = PI_HALF * li[j+64];
    float re2 = r2 * cosf(t2), im2 = r2 * sinf(t2);

    float B1[NU_], B2[NU_], B3[NU_], B4[NU_];
    {
        float s1 = expf(mult[j]),      s2 = expf(mult[j+128]);
        float s3 = expf(mult[j+64]),   s4 = expf(mult[j+192]);
        #pragma unroll
        for (int i = 0; i < NU_; i++) {
            B1[i] = B[(j      )*NU_ + i] * s1;
            B2[i] = B[(j + 128)*NU_ + i] * s2;
            B3[i] = B[(j +  64)*NU_ + i] * s3;
            B4[i] = B[(j + 192)*NU_ + i] * s4;
        }
    }

    float W1[NY_], W2[NY_], W3[NY_], W4[NY_];
    #pragma unroll
    for (int y = 0; y < NY_; y++) {
        W1[y] = Wx2y[y*NH_ + j      ];
        W2[y] = Wx2y[y*NH_ + j + 128];
        W3[y] = Wx2y[y*NH_ + j +  64];
        W4[y] = Wx2y[y*NH_ + j + 192];
    }
    const float biasv = bx2y[j & 7];

    __shared__ float uS[LCH*NU_];     // 512 B
    __shared__ float pS[64*17];       // 4352 B, stride 17: conflict-free
    if (j < 32) {
        int t = j >> 1, half = j & 1;
        float4 v = *(const float4*)(U + ((size_t)(k*LCH + t)*NB_ + b)*NU_ + half*4);
        ((float4*)uS)[j] = v;
    }

    const float* base = init_buf + ((size_t)(k*NB_ + b))*(H2_*2);
    float2 i1 = *(const float2*)(base + 2*j);
    float2 i2 = *(const float2*)(base + 128 + 2*j);
    float x1a=i1.x, x2a=i1.y, x1b=i2.x, x2b=i2.y;
    __syncthreads();

    float* outk = Y + ((size_t)k*LCH*NB_ + b)*NY_;

    #pragma unroll
    for (int tt = 0; tt < LCH/TT_; tt++) {
        float p[TT_*NY_];
        #pragma unroll
        for (int t4 = 0; t4 < TT_; t4++) {
            int t = tt*TT_ + t4;
            float4 u0 = ((const float4*)uS)[2*t+0];
            float4 u1 = ((const float4*)uS)[2*t+1];
            float u[NU_] = {u0.x,u0.y,u0.z,u0.w,u1.x,u1.y,u1.z,u1.w};
            float bu1=0.f, bu2=0.f, bu3=0.f, bu4=0.f;
            #pragma unroll
            for (int i = 0; i < NU_; i++) {
                bu1 = fmaf(u[i], B1[i], bu1);
                bu2 = fmaf(u[i], B2[i], bu2);
                bu3 = fmaf(u[i], B3[i], bu3);
                bu4 = fmaf(u[i], B4[i], bu4);
            }
            float n1a = fmaf(re1, x1a, fmaf(-im1, x2a, bu1));
            float n2a = fmaf(im1, x1a, fmaf( re1, x2a, bu2));
            float n1b = fmaf(re2, x1b, fmaf(-im2, x2b, bu3));
            float n2b = fmaf(im2, x1b, fmaf( re2, x2b, bu4));
            x1a=n1a; x2a=n2a; x1b=n1b; x2b=n2b;

            #pragma unroll
            for (int y = 0; y < NY_; y++) {
                p[t4*NY_ + y] = fmaf(x1a, W1[y], fmaf(x2a, W2[y],
                                fmaf(x1b, W3[y], x2b * W4[y])));
            }
        }
        // transpose-reduce through LDS: 16 scalar writes (stride 17, no conflict)
        float* row = pS + j*17;
        #pragma unroll
        for (int i = 0; i < TT_*NY_; i++) row[i] = p[i];
        __syncthreads();
        {
            const int c = j & 15;     // (t4,y) column
            const int g = j >> 4;     // row group (16 rows each)
            float s0=0.f, s1=0.f, s2=0.f, s3=0.f;
            #pragma unroll
            for (int s = 0; s < 16; s += 4) {
                s0 += pS[(g*16 + s+0)*17 + c];
                s1 += pS[(g*16 + s+1)*17 + c];
                s2 += pS[(g*16 + s+2)*17 + c];
                s3 += pS[(g*16 + s+3)*17 + c];
            }
            float sum = (s0+s1) + (s2+s3);
            sum += __shfl_xor(sum, 16, 64);
            sum += __shfl_xor(sum, 32, 64);
            if (j < 16) {
                int t4 = j >> 3, y = j & 7;
                outk[(size_t)(tt*TT_ + t4)*NB_*NY_ + y] = sum + biasv;
            }
        }
        __syncthreads();
    }
}

extern "C" void kernel_launch(void* const* d_in, const int* in_sizes, int n_in,
                              void* d_out, int out_size, void* d_ws, size_t ws_size,
                              hipStream_t stream) {
    const float* y0   = (const float*)d_in[0];
    const float* U    = (const float*)d_in[1];
    const float* lr   = (const float*)d_in[2];
    const float* li   = (const float*)d_in[3];
    const float* B    = (const float*)d_in[4];
    const float* mult = (const float*)d_in[5];
    const float* Wy2x = (const float*)d_in[6];
    const float* by2x = (const float*)d_in[7];
    const float* Wx2y = (const float*)d_in[8];
    const float* bx2y = (const float*)d_in[9];
    float* Y = (float*)d_out;

    float* c_buf    = (float*)d_ws;          // 8 MB
    float* init_buf = c_buf + BUF_FLOATS;    // 8 MB

    k_local <<<CCH*NB_, 64, 0, stream>>>(U, lr, li, B, mult, c_buf);
    k_prefix<<<(NB_*H2_)/64, 64, 0, stream>>>(y0, lr, li, Wy2x, by2x, c_buf, init_buf);
    k_emit  <<<CCH*NB_, 64, 0, stream>>>(U, lr, li, B, mult, Wx2y, bx2y, init_buf, Y);
}

// Round 4
// 111.970 us; speedup vs baseline: 2.9558x; 2.9558x over previous
//
#include <hip/hip_runtime.h>
#include <math.h>

#define T_   2048
#define NB_  64
#define NU_  8
#define NY_  8
#define NH_  256
#define H2_  128
#define CCH  64      // number of chunks
#define LCH  32      // chunk length = T_/CCH
#define TT_  2       // time tile in k_emit

#define BUF_FLOATS (CCH*NB_*H2_*2)   // [k][b][h2][2] = 1M floats = 4 MB
static const float PI_HALF = 1.5707963267948966f;

// Lane j owns pair j (channels j, j+128) and pair j+64 (channels j+64, j+192).

// ---------------- kernel 1: local chunk scan (zero init) ----------------
__global__ __launch_bounds__(64) void k_local(
    const float* __restrict__ U, const float* __restrict__ lr,
    const float* __restrict__ li, const float* __restrict__ B,
    const float* __restrict__ mult, float* __restrict__ c_buf)
{
    const int k = blockIdx.x >> 6;
    const int b = blockIdx.x & 63;
    const int j = threadIdx.x;

    float r1  = expf(-fabsf(lr[j]));
    float t1  = PI_HALF * li[j];
    float re1 = r1 * cosf(t1), im1 = r1 * sinf(t1);
    float r2  = expf(-fabsf(lr[j+64]));
    float t2  = PI_HALF * li[j+64];
    float re2 = r2 * cosf(t2), im2 = r2 * sinf(t2);

    float B1[NU_], B2[NU_], B3[NU_], B4[NU_];
    {
        float s1 = expf(mult[j]),      s2 = expf(mult[j+128]);
        float s3 = expf(mult[j+64]),   s4 = expf(mult[j+192]);
        #pragma unroll
        for (int i = 0; i < NU_; i++) {
            B1[i] = B[(j      )*NU_ + i] * s1;
            B2[i] = B[(j + 128)*NU_ + i] * s2;
            B3[i] = B[(j +  64)*NU_ + i] * s3;
            B4[i] = B[(j + 192)*NU_ + i] * s4;
        }
    }

    __shared__ float uS[LCH*NU_];   // [32][8] = 1 KB
    {
        int t = j >> 1, half = j & 1;
        float4 v = *(const float4*)(U + ((size_t)(k*LCH + t)*NB_ + b)*NU_ + half*4);
        ((float4*)uS)[j] = v;
    }
    __syncthreads();

    float x1a=0.f, x2a=0.f, x1b=0.f, x2b=0.f;
    #pragma unroll 8
    for (int t = 0; t < LCH; t++) {
        float4 u0 = ((const float4*)uS)[2*t+0];
        float4 u1 = ((const float4*)uS)[2*t+1];
        float u[NU_] = {u0.x,u0.y,u0.z,u0.w,u1.x,u1.y,u1.z,u1.w};
        float bu1=0.f, bu2=0.f, bu3=0.f, bu4=0.f;
        #pragma unroll
        for (int i = 0; i < NU_; i++) {
            bu1 = fmaf(u[i], B1[i], bu1);
            bu2 = fmaf(u[i], B2[i], bu2);
            bu3 = fmaf(u[i], B3[i], bu3);
            bu4 = fmaf(u[i], B4[i], bu4);
        }
        float n1a = fmaf(re1, x1a, fmaf(-im1, x2a, bu1));
        float n2a = fmaf(im1, x1a, fmaf( re1, x2a, bu2));
        float n1b = fmaf(re2, x1b, fmaf(-im2, x2b, bu3));
        float n2b = fmaf(im2, x1b, fmaf( re2, x2b, bu4));
        x1a=n1a; x2a=n2a; x1b=n1b; x2b=n2b;
    }

    float* base = c_buf + ((size_t)(k*NB_ + b))*(H2_*2);
    *(float2*)(base + 2*j)       = make_float2(x1a, x2a);
    *(float2*)(base + 128 + 2*j) = make_float2(x1b, x2b);
}

// ---------------- kernel 2: chunk prefix combine (separate in/out bufs) -------
__global__ __launch_bounds__(64) void k_prefix(
    const float* __restrict__ y0, const float* __restrict__ lr,
    const float* __restrict__ li, const float* __restrict__ Wy2x,
    const float* __restrict__ by2x, const float* __restrict__ c_buf,
    float* __restrict__ init_buf)
{
    const int g = blockIdx.x*64 + threadIdx.x;   // 0..8191
    const int b = g >> 7;
    const int h = g & 127;

    float x1 = by2x[h], x2 = by2x[h+H2_];
    #pragma unroll
    for (int y = 0; y < NY_; y++) {
        float yy = y0[b*NY_ + y];
        x1 = fmaf(yy, Wy2x[h*NY_ + y],        x1);
        x2 = fmaf(yy, Wy2x[(h+H2_)*NY_ + y],  x2);
    }

    float rL  = expf(-(float)LCH * fabsf(lr[h]));
    float thL = (float)LCH * PI_HALF * li[h];
    float reL = rL * cosf(thL), imL = rL * sinf(thL);

    const size_t stride = NB_*(size_t)(H2_*2);
    const size_t off    = (size_t)b*(H2_*2) + 2*h;

    #pragma unroll 8
    for (int k = 0; k < CCH; k++) {
        float2 c = *(const float2*)(c_buf + k*stride + off);   // independent loads
        *(float2*)(init_buf + k*stride + off) = make_float2(x1, x2);
        float n1 = fmaf(reL, x1, fmaf(-imL, x2, c.x));
        float n2 = fmaf(imL, x1, fmaf( reL, x2, c.y));
        x1 = n1; x2 = n2;
    }
}

// ---------------- kernel 3: replay with true init + tiled projection ----------
__global__ __launch_bounds__(64) void k_emit(
    const float* __restrict__ U, const float* __restrict__ lr,
    const float* __restrict__ li, const float* __restrict__ B,
    const float* __restrict__ mult, const float* __restrict__ Wx2y,
    const float* __restrict__ bx2y, const float* __restrict__ init_buf,
    float* __restrict__ Y)
{
    const int k = blockIdx.x >> 6;
    const int b = blockIdx.x & 63;
    const int j = threadIdx.x;

    float r1  = expf(-fabsf(lr[j]));
    float t1  = PI_HALF * li[j];
    float re1 = r1 * cosf(t1), im1 = r1 * sinf(t1);
    float r2  = expf(-fabsf(lr[j+64]));
    float t2  = PI_HALF * li[j+64];
    float re2 = r2 * cosf(t2), im2 = r2 * sinf(t2);

    float B1[NU_], B2[NU_], B3[NU_], B4[NU_];
    {
        float s1 = expf(mult[j]),      s2 = expf(mult[j+128]);
        float s3 = expf(mult[j+64]),   s4 = expf(mult[j+192]);
        #pragma unroll
        for (int i = 0; i < NU_; i++) {
            B1[i] = B[(j      )*NU_ + i] * s1;
            B2[i] = B[(j + 128)*NU_ + i] * s2;
            B3[i] = B[(j +  64)*NU_ + i] * s3;
            B4[i] = B[(j + 192)*NU_ + i] * s4;
        }
    }

    float W1[NY_], W2[NY_], W3[NY_], W4[NY_];
    #pragma unroll
    for (int y = 0; y < NY_; y++) {
        W1[y] = Wx2y[y*NH_ + j      ];
        W2[y] = Wx2y[y*NH_ + j + 128];
        W3[y] = Wx2y[y*NH_ + j +  64];
        W4[y] = Wx2y[y*NH_ + j + 192];
    }
    const float biasv = bx2y[j & 7];

    __shared__ float uS[LCH*NU_];     // 1 KB
    __shared__ float pS[64*17];       // 4352 B, stride 17: conflict-free
    {
        int t = j >> 1, half = j & 1;
        float4 v = *(const float4*)(U + ((size_t)(k*LCH + t)*NB_ + b)*NU_ + half*4);
        ((float4*)uS)[j] = v;
    }

    const float* base = init_buf + ((size_t)(k*NB_ + b))*(H2_*2);
    float2 i1 = *(const float2*)(base + 2*j);
    float2 i2 = *(const float2*)(base + 128 + 2*j);
    float x1a=i1.x, x2a=i1.y, x1b=i2.x, x2b=i2.y;
    __syncthreads();

    float* outk = Y + ((size_t)k*LCH*NB_ + b)*NY_;

    for (int tt = 0; tt < LCH/TT_; tt++) {
        float p[TT_*NY_];
        #pragma unroll
        for (int t4 = 0; t4 < TT_; t4++) {
            int t = tt*TT_ + t4;
            float4 u0 = ((const float4*)uS)[2*t+0];
            float4 u1 = ((const float4*)uS)[2*t+1];
            float u[NU_] = {u0.x,u0.y,u0.z,u0.w,u1.x,u1.y,u1.z,u1.w};
            float bu1=0.f, bu2=0.f, bu3=0.f, bu4=0.f;
            #pragma unroll
            for (int i = 0; i < NU_; i++) {
                bu1 = fmaf(u[i], B1[i], bu1);
                bu2 = fmaf(u[i], B2[i], bu2);
                bu3 = fmaf(u[i], B3[i], bu3);
                bu4 = fmaf(u[i], B4[i], bu4);
            }
            float n1a = fmaf(re1, x1a, fmaf(-im1, x2a, bu1));
            float n2a = fmaf(im1, x1a, fmaf( re1, x2a, bu2));
            float n1b = fmaf(re2, x1b, fmaf(-im2, x2b, bu3));
            float n2b = fmaf(im2, x1b, fmaf( re2, x2b, bu4));
            x1a=n1a; x2a=n2a; x1b=n1b; x2b=n2b;

            #pragma unroll
            for (int y = 0; y < NY_; y++) {
                p[t4*NY_ + y] = fmaf(x1a, W1[y], fmaf(x2a, W2[y],
                                fmaf(x1b, W3[y], x2b * W4[y])));
            }
        }
        // transpose-reduce through LDS: 16 scalar writes (stride 17, no conflict)
        float* row = pS + j*17;
        #pragma unroll
        for (int i = 0; i < TT_*NY_; i++) row[i] = p[i];
        __syncthreads();
        {
            const int c = j & 15;     // (t4,y) column
            const int g = j >> 4;     // row group (16 rows each)
            float s0=0.f, s1=0.f, s2=0.f, s3=0.f;
            #pragma unroll
            for (int s = 0; s < 16; s += 4) {
                s0 += pS[(g*16 + s+0)*17 + c];
                s1 += pS[(g*16 + s+1)*17 + c];
                s2 += pS[(g*16 + s+2)*17 + c];
                s3 += pS[(g*16 + s+3)*17 + c];
            }
            float sum = (s0+s1) + (s2+s3);
            sum += __shfl_xor(sum, 16, 64);
            sum += __shfl_xor(sum, 32, 64);
            if (j < 16) {
                int t4 = j >> 3, y = j & 7;
                outk[(size_t)(tt*TT_ + t4)*NB_*NY_ + y] = sum + biasv;
            }
        }
        __syncthreads();
    }
}

extern "C" void kernel_launch(void* const* d_in, const int* in_sizes, int n_in,
                              void* d_out, int out_size, void* d_ws, size_t ws_size,
                              hipStream_t stream) {
    const float* y0   = (const float*)d_in[0];
    const float* U    = (const float*)d_in[1];
    const float* lr   = (const float*)d_in[2];
    const float* li   = (const float*)d_in[3];
    const float* B    = (const float*)d_in[4];
    const float* mult = (const float*)d_in[5];
    const float* Wy2x = (const float*)d_in[6];
    const float* by2x = (const float*)d_in[7];
    const float* Wx2y = (const float*)d_in[8];
    const float* bx2y = (const float*)d_in[9];
    float* Y = (float*)d_out;

    float* c_buf    = (float*)d_ws;          // 4 MB
    float* init_buf = c_buf + BUF_FLOATS;    // 4 MB

    k_local <<<CCH*NB_, 64, 0, stream>>>(U, lr, li, B, mult, c_buf);
    k_prefix<<<(NB_*H2_)/64, 64, 0, stream>>>(y0, lr, li, Wy2x, by2x, c_buf, init_buf);
    k_emit  <<<CCH*NB_, 64, 0, stream>>>(U, lr, li, B, mult, Wx2y, bx2y, init_buf, Y);
}

// Round 6
// 107.540 us; speedup vs baseline: 3.0776x; 1.0412x over previous
//
#include <hip/hip_runtime.h>
#include <math.h>

#define T_   2048
#define NB_  64
#define NU_  8
#define NY_  8
#define NH_  256
#define H2_  128
#define CCH  64      // number of chunks
#define LCH  32      // chunk length = T_/CCH

#define BUF_FLOATS (CCH*NB_*H2_*2)   // [k][b][pair][2] = 1M floats = 4 MB
static const float PI_HALF = 1.5707963267948966f;

typedef _Float16 half8  __attribute__((ext_vector_type(8)));
typedef __fp16   fp16x2 __attribute__((ext_vector_type(2)));   // cvt_pkrtz return type
typedef float    f32x4  __attribute__((ext_vector_type(4)));

// Lane j owns pairs 2j, 2j+1  -> channels 2j, 2j+1, 2j+128, 2j+129.
// buf layout: [k][b][pair p][2] ; lane j writes float4 at offset 4j =
// (pair2j.x1, pair2j.x2, pair2j+1.x1, pair2j+1.x2)

// ---------------- kernel 1: local chunk scan (zero init) ----------------
__global__ __launch_bounds__(64) void k_local(
    const float* __restrict__ U, const float* __restrict__ lr,
    const float* __restrict__ li, const float* __restrict__ B,
    const float* __restrict__ mult, float* __restrict__ c_buf)
{
    const int k = blockIdx.x >> 6;
    const int b = blockIdx.x & 63;
    const int j = threadIdx.x;
    const int c0 = 2*j;

    float2 lrv = *(const float2*)(lr + c0);
    float2 liv = *(const float2*)(li + c0);
    float rA  = expf(-fabsf(lrv.x)), thA = PI_HALF*liv.x;
    float reA = rA*cosf(thA), imA = rA*sinf(thA);
    float rB  = expf(-fabsf(lrv.y)), thB = PI_HALF*liv.y;
    float reB = rB*cosf(thB), imB = rB*sinf(thB);

    float Ba1[NU_], Ba2[NU_], Bb1[NU_], Bb2[NU_];
    {
        float s1 = expf(mult[c0]),     s2 = expf(mult[c0+128]);
        float s3 = expf(mult[c0+1]),   s4 = expf(mult[c0+129]);
        #pragma unroll
        for (int i = 0; i < NU_; i++) {
            Ba1[i] = B[(c0    )*NU_ + i] * s1;
            Bb1[i] = B[(c0+  1)*NU_ + i] * s3;
            Ba2[i] = B[(c0+128)*NU_ + i] * s2;
            Bb2[i] = B[(c0+129)*NU_ + i] * s4;
        }
    }

    const float4* Ut = (const float4*)(U + ((size_t)(k*LCH)*NB_ + b)*NU_);
    // per-t stride = NB_*NU_/4 = 128 float4

    float xa1=0.f, xa2=0.f, xb1=0.f, xb2=0.f;
    #pragma unroll 4
    for (int t = 0; t < LCH; t++) {
        float4 u0 = Ut[t*128 + 0];     // wave-uniform broadcast load
        float4 u1 = Ut[t*128 + 1];
        float u[NU_] = {u0.x,u0.y,u0.z,u0.w,u1.x,u1.y,u1.z,u1.w};
        float ba1=0.f, ba2=0.f, bb1=0.f, bb2=0.f;
        #pragma unroll
        for (int i = 0; i < NU_; i++) {
            ba1 = fmaf(u[i], Ba1[i], ba1);
            ba2 = fmaf(u[i], Ba2[i], ba2);
            bb1 = fmaf(u[i], Bb1[i], bb1);
            bb2 = fmaf(u[i], Bb2[i], bb2);
        }
        float na1 = fmaf(reA, xa1, fmaf(-imA, xa2, ba1));
        float na2 = fmaf(imA, xa1, fmaf( reA, xa2, ba2));
        float nb1 = fmaf(reB, xb1, fmaf(-imB, xb2, bb1));
        float nb2 = fmaf(imB, xb1, fmaf( reB, xb2, bb2));
        xa1=na1; xa2=na2; xb1=nb1; xb2=nb2;
    }

    *(float4*)(c_buf + ((size_t)(k*NB_ + b))*(H2_*2) + 4*j) =
        make_float4(xa1, xa2, xb1, xb2);
}

// ---------------- kernel 2: chunk prefix combine ----------------
__global__ __launch_bounds__(64) void k_prefix(
    const float* __restrict__ y0, const float* __restrict__ lr,
    const float* __restrict__ li, const float* __restrict__ Wy2x,
    const float* __restrict__ by2x, const float* __restrict__ c_buf,
    float* __restrict__ init_buf)
{
    const int g = blockIdx.x*64 + threadIdx.x;   // 0..8191
    const int b = g >> 7;
    const int h = g & 127;                       // pair index

    float x1 = by2x[h], x2 = by2x[h+H2_];
    #pragma unroll
    for (int y = 0; y < NY_; y++) {
        float yy = y0[b*NY_ + y];
        x1 = fmaf(yy, Wy2x[h*NY_ + y],        x1);
        x2 = fmaf(yy, Wy2x[(h+H2_)*NY_ + y],  x2);
    }

    float rL  = expf(-(float)LCH * fabsf(lr[h]));
    float thL = (float)LCH * PI_HALF * li[h];
    float reL = rL * cosf(thL), imL = rL * sinf(thL);

    const size_t stride = NB_*(size_t)(H2_*2);
    const size_t off    = (size_t)b*(H2_*2) + 2*h;

    #pragma unroll 8
    for (int k = 0; k < CCH; k++) {
        float2 c = *(const float2*)(c_buf + k*stride + off);
        *(float2*)(init_buf + k*stride + off) = make_float2(x1, x2);
        float n1 = fmaf(reL, x1, fmaf(-imL, x2, c.x));
        float n2 = fmaf(imL, x1, fmaf( reL, x2, c.y));
        x1 = n1; x2 = n2;
    }
}

// ---------------- kernel 3: replay + MFMA projection ----------------
// X-tile in LDS: 16 rows (t) x 256 f16 chans, XOR-swizzled at 16B granularity:
//   dword (t, c-pair group) -> w0 = t*128 + ((j>>2)^t)*4 + (j&3), plus +64 for
//   the +128 channels. Banks 2-way max (free). Reads: b128 at row=l&15,
//   chunk p=((q*4+(l>>4)) ^ row) -> swizzle cancels into conflict-free b128.
__global__ __launch_bounds__(64) void k_emit(
    const float* __restrict__ U, const float* __restrict__ lr,
    const float* __restrict__ li, const float* __restrict__ B,
    const float* __restrict__ mult, const float* __restrict__ Wx2y,
    const float* __restrict__ bx2y, const float* __restrict__ init_buf,
    float* __restrict__ Y)
{
    const int k = blockIdx.x >> 6;
    const int b = blockIdx.x & 63;
    const int j = threadIdx.x;
    const int c0 = 2*j;

    float2 lrv = *(const float2*)(lr + c0);
    float2 liv = *(const float2*)(li + c0);
    float rA  = expf(-fabsf(lrv.x)), thA = PI_HALF*liv.x;
    float reA = rA*cosf(thA), imA = rA*sinf(thA);
    float rB  = expf(-fabsf(lrv.y)), thB = PI_HALF*liv.y;
    float reB = rB*cosf(thB), imB = rB*sinf(thB);

    float Ba1[NU_], Ba2[NU_], Bb1[NU_], Bb2[NU_];
    {
        float s1 = expf(mult[c0]),     s2 = expf(mult[c0+128]);
        float s3 = expf(mult[c0+1]),   s4 = expf(mult[c0+129]);
        #pragma unroll
        for (int i = 0; i < NU_; i++) {
            Ba1[i] = B[(c0    )*NU_ + i] * s1;
            Bb1[i] = B[(c0+  1)*NU_ + i] * s3;
            Ba2[i] = B[(c0+128)*NU_ + i] * s2;
            Bb2[i] = B[(c0+129)*NU_ + i] * s4;
        }
    }

    // B-operand fragments: B[k=chan][n=y] = Wx2y[y][chan], f16.
    // Lane l holds k = q*32 + (l>>4)*8 + i, n = l&15 (cols 8..15 zero-padded).
    const int yv  = j & 15;
    const int kg  = j >> 4;
    const int row = yv;            // A row / C col group
    half8 wf[8];
    #pragma unroll
    for (int q = 0; q < 8; q++) {
        half8 f;
        if (yv < 8) {
            const float* wr = Wx2y + yv*NH_ + q*32 + kg*8;
            #pragma unroll
            for (int i = 0; i < 8; i++) f[i] = (_Float16)wr[i];
        } else {
            #pragma unroll
            for (int i = 0; i < 8; i++) f[i] = (_Float16)0.f;
        }
        wf[q] = f;
    }
    const float bias = bx2y[yv & 7];

    __shared__ _Float16 xS[16*256];       // 8 KB
    uint32_t* xS32 = (uint32_t*)xS;

    float4 ini = *(const float4*)(init_buf + ((size_t)(k*NB_ + b))*(H2_*2) + 4*j);
    float xa1=ini.x, xa2=ini.y, xb1=ini.z, xb2=ini.w;

    const float4* Ut = (const float4*)(U + ((size_t)(k*LCH)*NB_ + b)*NU_);

    for (int s = 0; s < LCH/16; s++) {
        #pragma unroll 4
        for (int t16 = 0; t16 < 16; t16++) {
            const int t = s*16 + t16;
            float4 u0 = Ut[t*128 + 0];    // broadcast loads (VMEM pipe)
            float4 u1 = Ut[t*128 + 1];
            float u[NU_] = {u0.x,u0.y,u0.z,u0.w,u1.x,u1.y,u1.z,u1.w};
            float ba1=0.f, ba2=0.f, bb1=0.f, bb2=0.f;
            #pragma unroll
            for (int i = 0; i < NU_; i++) {
                ba1 = fmaf(u[i], Ba1[i], ba1);
                ba2 = fmaf(u[i], Ba2[i], ba2);
                bb1 = fmaf(u[i], Bb1[i], bb1);
                bb2 = fmaf(u[i], Bb2[i], bb2);
            }
            float na1 = fmaf(reA, xa1, fmaf(-imA, xa2, ba1));
            float na2 = fmaf(imA, xa1, fmaf( reA, xa2, ba2));
            float nb1 = fmaf(reB, xb1, fmaf(-imB, xb2, bb1));
            float nb2 = fmaf(imB, xb1, fmaf( reB, xb2, bb2));
            xa1=na1; xa2=na2; xb1=nb1; xb2=nb2;

            union { fp16x2 h; uint32_t u32; } p0, p1;
            p0.h = __builtin_amdgcn_cvt_pkrtz(xa1, xb1);   // chans 2j, 2j+1
            p1.h = __builtin_amdgcn_cvt_pkrtz(xa2, xb2);   // chans 2j+128, 2j+129
            const int w0 = t16*128 + (((j>>2) ^ t16) << 2) + (j & 3);
            xS32[w0]      = p0.u32;
            xS32[w0 + 64] = p1.u32;
        }
        __syncthreads();

        f32x4 acc = {0.f, 0.f, 0.f, 0.f};
        #pragma unroll
        for (int q = 0; q < 8; q++) {
            const int p = ((q << 2) + kg) ^ row;
            const half8* ap = (const half8*)(xS + (row << 8) + (p << 3));
            acc = __builtin_amdgcn_mfma_f32_16x16x32_f16(*ap, wf[q], acc, 0, 0, 0);
        }
        __syncthreads();

        if (yv < 8) {
            #pragma unroll
            for (int r = 0; r < 4; r++) {
                const int tg = k*LCH + s*16 + kg*4 + r;   // C row = t
                Y[((size_t)tg*NB_ + b)*NY_ + yv] = acc[r] + bias;
            }
        }
    }
}

extern "C" void kernel_launch(void* const* d_in, const int* in_sizes, int n_in,
                              void* d_out, int out_size, void* d_ws, size_t ws_size,
                              hipStream_t stream) {
    const float* y0   = (const float*)d_in[0];
    const float* U    = (const float*)d_in[1];
    const float* lr   = (const float*)d_in[2];
    const float* li   = (const float*)d_in[3];
    const float* B    = (const float*)d_in[4];
    const float* mult = (const float*)d_in[5];
    const float* Wy2x = (const float*)d_in[6];
    const float* by2x = (const float*)d_in[7];
    const float* Wx2y = (const float*)d_in[8];
    const float* bx2y = (const float*)d_in[9];
    float* Y = (float*)d_out;

    float* c_buf    = (float*)d_ws;          // 4 MB
    float* init_buf = c_buf + BUF_FLOATS;    // 4 MB

    k_local <<<CCH*NB_, 64, 0, stream>>>(U, lr, li, B, mult, c_buf);
    k_prefix<<<(NB_*H2_)/64, 64, 0, stream>>>(y0, lr, li, Wy2x, by2x, c_buf, init_buf);
    k_emit  <<<CCH*NB_, 64, 0, stream>>>(U, lr, li, B, mult, Wx2y, bx2y, init_buf, Y);
}